// Round 8
// baseline (254.568 us; speedup 1.0000x reference)
//
#include <hip/hip_runtime.h>
#include <hip/hip_fp16.h>

#define FDIM 128
#define HEADS 4
#define CD 32
#define BM 64
#define NBKT 256        // destination buckets (32 per XCD group)

typedef __attribute__((ext_vector_type(8))) short bfrag;   // 8 bf16 (4 VGPRs)
typedef __attribute__((ext_vector_type(4))) float ffrag;   // 4 f32 accum

static __device__ __forceinline__ unsigned short f2bf(float v) {
    unsigned u = __float_as_uint(v);
    u += 0x7FFF + ((u >> 16) & 1);          // round-nearest-even
    return (unsigned short)(u >> 16);
}
static __device__ __forceinline__ float bf2f(unsigned short u) {
    return __uint_as_float(((unsigned)u) << 16);
}

// K0: split W into bf16 hi/lo, transpose to [n][k].
__global__ __launch_bounds__(256) void k_wsplit(const float* __restrict__ w,
                                                unsigned short* __restrict__ wt_hi,
                                                unsigned short* __restrict__ wt_lo)
{
    int i = blockIdx.x * 256 + threadIdx.x;
    float v = w[i];
    unsigned short h = f2bf(v);
    float r = v - bf2f(h);
    int k = i >> 7, n = i & 127;
    wt_hi[n * FDIM + k] = h;
    wt_lo[n * FDIM + k] = f2bf(r);
}

// K0b: per-chunk x DST-bucket histogram. LDS atomics only.
__global__ __launch_bounds__(256) void k_hist(const int* __restrict__ ei, int E, int N,
                                              int* __restrict__ cntT, int nch)
{
    __shared__ int h[NBKT];
    int t = threadIdx.x, chunk = blockIdx.x;
    h[t] = 0;
    __syncthreads();
    int e = chunk * 256 + t;
    if (e < E) atomicAdd(&h[(ei[E + e] * NBKT) / N], 1);
    __syncthreads();
    cntT[t * nch + chunk] = h[t];
}

// K0c: block b: exclusive scan of cntT[b][*] -> boffT[b][*]; total -> btot[b].
__global__ __launch_bounds__(256) void k_scanA(const int* __restrict__ cntT,
                                               int* __restrict__ boffT,
                                               int* __restrict__ btot, int nch)
{
    __shared__ int ws[4];
    int t = threadIdx.x, lane = t & 63, w = t >> 6, b = blockIdx.x;
    int carry = 0;
    for (int c0 = 0; c0 < nch; c0 += 256) {
        int idx = c0 + t;
        int v = (idx < nch) ? cntT[b * nch + idx] : 0;
        int x = v;
#pragma unroll
        for (int d = 1; d < 64; d <<= 1) { int y = __shfl_up(x, d, 64); if (lane >= d) x += y; }
        if (lane == 63) ws[w] = x;
        __syncthreads();
        int woff = 0;
        for (int i = 0; i < w; i++) woff += ws[i];
        int tot = ws[0] + ws[1] + ws[2] + ws[3];
        if (idx < nch) boffT[b * nch + idx] = carry + woff + (x - v);
        carry += tot;
        __syncthreads();
    }
    if (t == 0) btot[b] = carry;
}

// K0d: exclusive scan of 256 bucket totals -> bbase[257].
__global__ __launch_bounds__(256) void k_scanB(const int* __restrict__ btot,
                                               int* __restrict__ bbase, int E)
{
    __shared__ int ws[4];
    int t = threadIdx.x, lane = t & 63, w = t >> 6;
    int v = btot[t];
    int x = v;
#pragma unroll
    for (int d = 1; d < 64; d <<= 1) { int y = __shfl_up(x, d, 64); if (lane >= d) x += y; }
    if (lane == 63) ws[w] = x;
    __syncthreads();
    int woff = 0;
    for (int i = 0; i < w; i++) woff += ws[i];
    bbase[t] = woff + (x - v);
    if (t == 255) bbase[256] = E;
}

// K0e: deterministic DST-bucket placement (LDS rank only). rec = (r, cl) 8B.
__global__ __launch_bounds__(256) void k_place(const int* __restrict__ ei, int E, int N,
                                               const int* __restrict__ boffT,
                                               const int* __restrict__ bbase,
                                               uint2* __restrict__ recs, int nch)
{
    __shared__ int sOff[NBKT];
    __shared__ int lcnt[NBKT];
    int t = threadIdx.x, chunk = blockIdx.x;
    sOff[t] = bbase[t] + boffT[t * nch + chunk];
    lcnt[t] = 0;
    __syncthreads();
    int e = chunk * 256 + t;
    if (e < E) {
        int r = ei[e], cl = ei[E + e];
        int b = (cl * NBKT) / N;
        int pos = sOff[b] + atomicAdd(&lcnt[b], 1);
        recs[pos] = make_uint2((unsigned)r, (unsigned)cl);
    }
}

// K1: MFMA GEMM (split bf16: hi*hi + hi*lo + lo*hi ~= fp32) + logits.
// Prologue zeroes seg (N*4 f32) + out_acc2 (N*16 half2), contiguous.
__global__ __launch_bounds__(256) void k_gemm(const float* __restrict__ x,
                                              const unsigned short* __restrict__ wt_hi,
                                              const unsigned short* __restrict__ wt_lo,
                                              const float* __restrict__ att,
                                              unsigned short* __restrict__ xwh,
                                              float* __restrict__ a_src,
                                              float* __restrict__ a_dst,
                                              float4* __restrict__ zero_base,
                                              int nz4, int N)
{
    __shared__ float accs[BM * 132];
    __shared__ float attl[HEADS * 2 * CD];
    int t = threadIdx.x;
    int row0 = blockIdx.x * BM;
    for (int i = blockIdx.x * 256 + t; i < nz4; i += gridDim.x * 256)
        zero_base[i] = make_float4(0.f, 0.f, 0.f, 0.f);
    attl[t] = att[t];

    int l = t & 63, wv = t >> 6;
    int la = l & 15, lr = l >> 4;
    int arow = row0 + wv * 16 + la;
    bool aval = arow < N;
    const float* xbase = x + (size_t)arow * FDIM + lr * 8;

    ffrag acc[8] = {};
#pragma unroll
    for (int ks = 0; ks < 4; ks++) {
        float xv[8] = {0.f, 0.f, 0.f, 0.f, 0.f, 0.f, 0.f, 0.f};
        if (aval) {
            float4 f0 = *(const float4*)(xbase + ks * 32);
            float4 f1 = *(const float4*)(xbase + ks * 32 + 4);
            xv[0] = f0.x; xv[1] = f0.y; xv[2] = f0.z; xv[3] = f0.w;
            xv[4] = f1.x; xv[5] = f1.y; xv[6] = f1.z; xv[7] = f1.w;
        }
        bfrag ah, al;
#pragma unroll
        for (int j = 0; j < 8; j++) {
            unsigned short h = f2bf(xv[j]);
            ah[j] = (short)h;
            al[j] = (short)f2bf(xv[j] - bf2f(h));
        }
        int boffk = ks * 32 + lr * 8;
#pragma unroll
        for (int ct = 0; ct < 8; ct++) {
            int o = (ct * 16 + la) * FDIM + boffk;
            bfrag bh = *(const bfrag*)(wt_hi + o);
            bfrag bl = *(const bfrag*)(wt_lo + o);
            acc[ct] = __builtin_amdgcn_mfma_f32_16x16x32_bf16(ah, bh, acc[ct], 0, 0, 0);
            acc[ct] = __builtin_amdgcn_mfma_f32_16x16x32_bf16(ah, bl, acc[ct], 0, 0, 0);
            acc[ct] = __builtin_amdgcn_mfma_f32_16x16x32_bf16(al, bh, acc[ct], 0, 0, 0);
        }
    }

#pragma unroll
    for (int i = 0; i < 4; i++) {
        int r = row0 + wv * 16 + lr * 4 + i;
        if (r < N) {
            uint2 pa, pb;
            pa.x = (unsigned)f2bf(acc[0][i]) | ((unsigned)f2bf(acc[2][i]) << 16);
            pa.y = (unsigned)f2bf(acc[4][i]) | ((unsigned)f2bf(acc[6][i]) << 16);
            pb.x = (unsigned)f2bf(acc[1][i]) | ((unsigned)f2bf(acc[3][i]) << 16);
            pb.y = (unsigned)f2bf(acc[5][i]) | ((unsigned)f2bf(acc[7][i]) << 16);
            *(uint2*)&xwh[(size_t)r * FDIM + la * 4] = pa;
            *(uint2*)&xwh[(size_t)r * FDIM + 64 + la * 4] = pb;
        }
    }
#pragma unroll
    for (int ct = 0; ct < 8; ct++)
#pragma unroll
        for (int i = 0; i < 4; i++)
            accs[(wv * 16 + lr * 4 + i) * 132 + ct * 16 + la] = acc[ct][i];
    __syncthreads();
    int row = t >> 2, h = t & 3;
    const float* ap = &attl[h * 2 * CD];
    const float* xr = &accs[row * 132 + h * CD];
    float s = 0.f, d = 0.f;
#pragma unroll 8
    for (int c = 0; c < CD; c++) { float v = xr[c]; s += v * ap[c]; d += v * ap[CD + c]; }
    int n = row0 + row;
    if (n < N) { a_src[n * 4 + h] = s; a_dst[n * 4 + h] = d; }
}

// K2: seg only (round-1 form, leaner: no ealpha, no cnt). Lane-per-(edge,head):
// 4 adjacent lanes share one 16B sector -> coalesced atomic groups.
__global__ __launch_bounds__(256) void k_esum(const int* __restrict__ ei, int E,
                                              const float* __restrict__ a_src,
                                              const float* __restrict__ a_dst,
                                              float* __restrict__ seg)
{
    int gid = blockIdx.x * 256 + threadIdx.x;
    if (gid >= E * HEADS) return;
    int e = gid >> 2, h = gid & 3;
    int r = ei[e], cl = ei[E + e];
    float a = a_src[r * 4 + h] + a_dst[cl * 4 + h];
    a = a >= 0.f ? a : 0.2f * a;
    atomicAdd(&seg[r * 4 + h], __expf(a));
}

// K3: DST-XCD-pinned scatter. Block bid handles bucket group bid%8 (32 buckets =
// one N/8 dst slice); round-robin dispatch pins each group to one XCD, so all
// atomics from an XCD land in its own 400KB out_acc2 slice. Alpha recomputed
// from L2-resident a_src/a_dst/seg; normalization (0.25/(seg+eps)) inline.
__global__ __launch_bounds__(256) void k_scatter(const uint2* __restrict__ recs,
                                                 const int* __restrict__ bbase,
                                                 const float* __restrict__ a_src,
                                                 const float* __restrict__ a_dst,
                                                 const float* __restrict__ seg,
                                                 const unsigned short* __restrict__ xwh,
                                                 __half2* __restrict__ out_acc2, int bpg)
{
    int t = threadIdx.x;
    int le = t >> 4, c2 = t & 15, lane = t & 63;   // 16 edges/block
    int j = blockIdx.x & 7;
    int lo = bbase[j * 32], hi = bbase[(j + 1) * 32];
    for (int chunk = blockIdx.x >> 3; lo + chunk * 16 < hi; chunk += bpg) {
        int idx = lo + chunk * 16 + le;
        bool v = idx < hi;
        uint2 rec = recs[v ? idx : lo];
        int r = (int)rec.x, cl = (int)rec.y;
        float av = 0.f;
        if (v && c2 < 4) {
            float a = a_src[r * 4 + c2] + a_dst[cl * 4 + c2];
            a = a >= 0.f ? a : 0.2f * a;
            av = __expf(a) * 0.25f / (seg[r * 4 + c2] + 1e-16f);
        }
        uint4 q = ((const uint4*)(xwh + (size_t)r * FDIM))[c2];
        float a0 = __shfl(av, (lane & 48) + 0, 64);
        float a1 = __shfl(av, (lane & 48) + 1, 64);
        float a2 = __shfl(av, (lane & 48) + 2, 64);
        float a3 = __shfl(av, (lane & 48) + 3, 64);
        float v0 = a0 * bf2f((unsigned short)(q.x & 0xFFFF)) + a1 * bf2f((unsigned short)(q.x >> 16))
                 + a2 * bf2f((unsigned short)(q.y & 0xFFFF)) + a3 * bf2f((unsigned short)(q.y >> 16));
        float v1 = a0 * bf2f((unsigned short)(q.z & 0xFFFF)) + a1 * bf2f((unsigned short)(q.z >> 16))
                 + a2 * bf2f((unsigned short)(q.w & 0xFFFF)) + a3 * bf2f((unsigned short)(q.w >> 16));
        if (v) unsafeAtomicAdd(&out_acc2[(size_t)cl * 16 + c2], __floats2half2_rn(v0, v1));
    }
}

// K4: out = fp16 out_acc2 + bias
__global__ void k_final(const __half2* __restrict__ out_acc2, const float4* __restrict__ bias,
                        float4* __restrict__ out, int N)
{
    int i = blockIdx.x * 256 + threadIdx.x;
    if (i >= N * 8) return;
    float4 b = bias[i & 7];
    float2 f0 = __half22float2(out_acc2[i * 2]);
    float2 f1 = __half22float2(out_acc2[i * 2 + 1]);
    out[i] = make_float4(f0.x + b.x, f0.y + b.y, f1.x + b.z, f1.y + b.w);
}

extern "C" void kernel_launch(void* const* d_in, const int* in_sizes, int n_in,
                              void* d_out, int out_size, void* d_ws, size_t ws_size,
                              hipStream_t stream)
{
    const float* x    = (const float*)d_in[0];
    const int*   ei   = (const int*)d_in[1];
    const float* w    = (const float*)d_in[2];
    const float* att  = (const float*)d_in[3];
    const float* bias = (const float*)d_in[4];
    float* out = (float*)d_out;
    int N = in_sizes[0] / FDIM;
    int E = in_sizes[1] / 2;
    int nch = (E + 255) / 256;                    // 3125 for E=800000

    // layout (16B aligned); seg and out_acc2 contiguous for the gemm zero-prologue
    unsigned short* xwh = (unsigned short*)d_ws;              // N*128 bf16  (12.8 MB)
    uint2* recs  = (uint2*)(xwh + (size_t)N * FDIM);          // E*8B dst-sorted (6.4 MB)
    float* a_src = (float*)(recs + (size_t)E);                // N*4 f32
    float* a_dst = a_src + (size_t)N * HEADS;                 // N*4 f32
    float* seg   = a_dst + (size_t)N * HEADS;                 // N*4 f32   (zeroed)
    __half2* out_acc2 = (__half2*)(seg + (size_t)N * HEADS);  // N*16 half2 (zeroed, contig)
    unsigned short* wt_hi = (unsigned short*)(out_acc2 + (size_t)N * 16);
    unsigned short* wt_lo = wt_hi + FDIM * FDIM;
    int* btot  = (int*)(wt_lo + FDIM * FDIM);                 // 256
    int* bbase = btot + NBKT;                                 // 257 (+pad)
    int* cntT  = bbase + NBKT + 8;                            // 256*nch ints
    int* boffT = cntT + (size_t)NBKT * nch;                   // 256*nch ints

    int nz4 = N * 5;   // seg N*4 f32 (N float4) + out_acc2 N*64B (N*4 float4)
    int bpg = (E / 8 + E / 64 + 15) / 16;  // blocks per dst group, ~12% headroom

    k_wsplit<<<(FDIM * FDIM) / 256, 256, 0, stream>>>(w, wt_hi, wt_lo);
    k_hist<<<nch, 256, 0, stream>>>(ei, E, N, cntT, nch);
    k_scanA<<<NBKT, 256, 0, stream>>>(cntT, boffT, btot, nch);
    k_scanB<<<1, 256, 0, stream>>>(btot, bbase, E);
    k_place<<<nch, 256, 0, stream>>>(ei, E, N, boffT, bbase, recs, nch);
    k_gemm<<<(N + BM - 1) / BM, 256, 0, stream>>>(x, wt_hi, wt_lo, att, xwh, a_src, a_dst,
                                                  (float4*)seg, nz4, N);
    k_esum<<<(E * HEADS + 255) / 256, 256, 0, stream>>>(ei, E, a_src, a_dst, seg);
    k_scatter<<<8 * bpg, 256, 0, stream>>>(recs, bbase, a_src, a_dst, seg, xwh, out_acc2, bpg);
    k_final<<<(N * 8 + 255) / 256, 256, 0, stream>>>(out_acc2, (const float4*)bias,
                                                     (float4*)out, N);
}